// Round 2
// baseline (607.226 us; speedup 1.0000x reference)
//
#include <hip/hip_runtime.h>

#define NN     200000
#define MPAD   200064   // 1563 * 128
#define KDIM   256
#define NHEAD  8
#define NGRAPH 1024
#define APAD   264      // padded LDS row for alpha kernel

typedef __bf16 bf16x8 __attribute__((ext_vector_type(8)));
typedef float  f32x4  __attribute__((ext_vector_type(4)));

// ---------- helpers ----------
__device__ __forceinline__ unsigned short f2bu(float f) {
    unsigned u = __float_as_uint(f);
    unsigned r = (u + 0x7FFFu + ((u >> 16) & 1u)) >> 16;
    return (unsigned short)r;
}
__device__ __forceinline__ float b2f(unsigned short u) {
    return __uint_as_float(((unsigned)u) << 16);
}
__device__ __forceinline__ void async16(const void* g, void* l) {
    __builtin_amdgcn_global_load_lds(
        (const __attribute__((address_space(1))) void*)g,
        (__attribute__((address_space(3))) void*)l, 16, 0, 0);
}

// ---------- kernel 1: cast x -> bf16, zero the 64 pad rows ----------
__global__ __launch_bounds__(256) void convert_x(const float* __restrict__ x,
                                                 unsigned short* __restrict__ xb) {
    size_t e = ((size_t)blockIdx.x * 256 + threadIdx.x) * 4;
    ushort4 o;
    if (e < (size_t)NN * 256) {
        float4 v = *(const float4*)(x + e);
        o.x = f2bu(v.x); o.y = f2bu(v.y); o.z = f2bu(v.z); o.w = f2bu(v.w);
    } else {
        o.x = o.y = o.z = o.w = 0;
    }
    *(ushort4*)(xb + e) = o;
}

// ---------- kernel 2: transpose-convert weights, build concat bias ----------
__global__ __launch_bounds__(256) void convert_w(
    const float* __restrict__ Wg1, const float* __restrict__ Wn1,
    const float* __restrict__ Wn2, const float* __restrict__ bn1,
    unsigned short* __restrict__ wcatT, unsigned short* __restrict__ wn2T,
    float* __restrict__ biascat) {
    int i = blockIdx.x * 256 + threadIdx.x;
    if (i < 512 * 256) {                       // wcatT[n][k] = Wcat[k][n]
        int n = i >> 8, k = i & 255;
        float v = (n < 256) ? Wg1[k * 256 + n] : Wn1[k * 256 + (n - 256)];
        wcatT[i] = f2bu(v);
    } else if (i < 512 * 256 + 256 * 256) {    // wn2T[c][k] = Wn2[k][c]
        int j = i - 512 * 256;
        int n = j >> 8, k = j & 255;
        wn2T[j] = f2bu(Wn2[k * 256 + n]);
    } else if (i < 512 * 256 + 256 * 256 + 512) {
        int b = i - (512 * 256 + 256 * 256);
        biascat[b] = (b < 256) ? 0.0f : bn1[b - 256];
    }
}

// ---------- kernel 3/4: bf16 MFMA GEMM, C = act(A @ Bt^T + bias) ----------
// A: [rows, lda] bf16 row-major.  Bt: [ncols, 256] bf16 (B transposed).
// 128x128 tile, BK=64, 4 waves (2x2), each wave 4x4 of 16x16x32 MFMA x2 kk.
// LDS rows are 64 elems (128 B); 16-B chunk c of row r stored at slot c^(r&7)
// (swizzle applied on the GLOBAL source address — global_load_lds packs lanes
// contiguously, so LDS placement is fixed; we permute what each lane fetches).
// Fragment reads then spread all 32 banks per 8-lane phase: conflict-free.
__global__ __launch_bounds__(256) void gemm_bt(
    const unsigned short* __restrict__ A, int lda,
    const unsigned short* __restrict__ Bt,
    const float* __restrict__ bias,
    unsigned short* __restrict__ C, int ldc, int do_relu) {
    __shared__ unsigned short As[128 * 64];   // 16 KB
    __shared__ unsigned short Bs[128 * 64];   // 16 KB
    const int tid  = threadIdx.x;
    const int lane = tid & 63;
    const int wave = tid >> 6;
    const int wm = wave >> 1, wn = wave & 1;
    const size_t m0 = (size_t)blockIdx.y * 128;
    const int    n0 = blockIdx.x * 128;

    // staging: per wave 32 rows of each tile; 4 issues x 8 rows x 8 chunks
    const int schunk = lane & 7;                  // 16-B chunk slot in LDS row
    const int srow0  = wave * 32 + (lane >> 3);   // rows step +8 per issue
    const int sw = ((schunk ^ (srow0 & 7)) * 8);  // swizzled global col (elems)
    const unsigned short* gA = A + (m0 + srow0) * (size_t)lda + sw;
    const unsigned short* gB = Bt + (size_t)(n0 + srow0) * KDIM + sw;
    unsigned short* lA = As + wave * 2048;        // HW adds lane*16 B
    unsigned short* lB = Bs + wave * 2048;

    f32x4 acc[4][4] = {};
    const int frow = lane & 15;
    const int quad = lane >> 4;
    const int arow = wm * 64 + frow;
    const int brow = wn * 64 + frow;

    for (int k0 = 0; k0 < KDIM; k0 += 64) {
        #pragma unroll
        for (int is = 0; is < 4; ++is) {
            async16(gA + (size_t)(is * 8) * lda + k0, lA + is * 512);
            async16(gB + (is * 8) * KDIM + k0, lB + is * 512);
        }
        __syncthreads();           // drains vmcnt before LDS use
        #pragma unroll
        for (int kk = 0; kk < 2; ++kk) {
            const int s = (quad + kk * 4) ^ (frow & 7);   // swizzled slot
            bf16x8 af[4], bf[4];
            #pragma unroll
            for (int i = 0; i < 4; ++i)
                af[i] = *(const bf16x8*)(As + (arow + i * 16) * 64 + s * 8);
            #pragma unroll
            for (int j = 0; j < 4; ++j)
                bf[j] = *(const bf16x8*)(Bs + (brow + j * 16) * 64 + s * 8);
            #pragma unroll
            for (int i = 0; i < 4; ++i)
                #pragma unroll
                for (int j = 0; j < 4; ++j)
                    acc[i][j] = __builtin_amdgcn_mfma_f32_16x16x32_bf16(
                        af[i], bf[j], acc[i][j], 0, 0, 0);
        }
        __syncthreads();           // protect LDS before next stage
    }

    float bv[4];
    #pragma unroll
    for (int j = 0; j < 4; ++j) bv[j] = bias[n0 + wn * 64 + j * 16 + frow];
    const int rbase = wm * 64 + (quad << 2);
    #pragma unroll
    for (int i = 0; i < 4; ++i) {
        #pragma unroll
        for (int r = 0; r < 4; ++r) {
            size_t row = m0 + rbase + i * 16 + r;
            #pragma unroll
            for (int j = 0; j < 4; ++j) {
                float v = acc[i][j][r] + bv[j];
                if (do_relu) v = fmaxf(v, 0.0f);
                C[row * ldc + (n0 + wn * 64 + j * 16 + frow)] = f2bu(v);
            }
        }
    }
}

// ---------- kernel 5: alpha = h_g @ Wg2  (fp32 accum, LDS-staged) ----------
__global__ __launch_bounds__(256) void alpha_kernel(
    const unsigned short* __restrict__ h,   // [MPAD,512], cols 0..255 = h_g
    const float* __restrict__ Wg2,          // [256,8] fp32
    float* __restrict__ alpha) {            // [NN,8]
    __shared__ unsigned short hs[64 * APAD];
    __shared__ float wg[256 * 8];
    const int t = threadIdx.x;
    const size_t n0 = (size_t)blockIdx.x * 64;
    for (int i = t; i < 2048; i += 256) wg[i] = Wg2[i];
    #pragma unroll
    for (int it = 0; it < 16; ++it) {
        int e = (t + it * 256) * 4;
        int r = e >> 8, c = e & 255;
        *(ushort4*)&hs[r * APAD + c] = *(const ushort4*)(h + (n0 + r) * 512 + c);
    }
    __syncthreads();
    const int nl = t >> 2;        // node 0..63
    const int hp = t & 3;         // heads hp, hp+4
    float a0 = 0.f, a1 = 0.f;
    #pragma unroll 8
    for (int k = 0; k < 256; ++k) {
        float xv = b2f(hs[nl * APAD + k]);
        a0 += xv * wg[k * 8 + hp];
        a1 += xv * wg[k * 8 + hp + 4];
    }
    alpha[(n0 + nl) * 8 + hp]     = a0;
    alpha[(n0 + nl) * 8 + hp + 4] = a1;
}

// ---------- kernel 6: per-graph softmax + gated pooling ----------
__device__ __forceinline__ int lower_bound(const int* __restrict__ b, int key) {
    int lo = 0, hi = NN;
    while (lo < hi) { int mid = (lo + hi) >> 1; if (b[mid] < key) lo = mid + 1; else hi = mid; }
    return lo;
}

__global__ __launch_bounds__(256) void pool_kernel(
    const float* __restrict__ alpha, const unsigned short* __restrict__ feats,
    const int* __restrict__ batch, float* __restrict__ out) {
    __shared__ float red[256];
    __shared__ float mh[8], ih[8];
    const int g = blockIdx.x, t = threadIdx.x;
    const int start = lower_bound(batch, g);
    const int end   = lower_bound(batch, g + 1);
    const int hd = t & 7;

    float mloc = -INFINITY;
    for (int n = start + (t >> 3); n < end; n += 32)
        mloc = fmaxf(mloc, alpha[n * 8 + hd]);
    red[t] = mloc; __syncthreads();
    for (int off = 128; off >= 8; off >>= 1) {
        if (t < off) red[t] = fmaxf(red[t], red[t + off]);
        __syncthreads();
    }
    if (t < 8) mh[t] = red[t];
    __syncthreads();
    const float mm = mh[hd];

    float sloc = 0.f;
    for (int n = start + (t >> 3); n < end; n += 32)
        sloc += __expf(alpha[n * 8 + hd] - mm);
    red[t] = sloc; __syncthreads();
    for (int off = 128; off >= 8; off >>= 1) {
        if (t < off) red[t] += red[t + off];
        __syncthreads();
    }
    if (t < 8) ih[t] = 1.0f / (red[t] + 1e-16f);
    __syncthreads();
    const float inv = ih[hd];

    float acc = 0.f;
    for (int n = start; n < end; ++n) {
        float gate = __expf(alpha[n * 8 + hd] - mm) * inv;
        acc += gate * b2f(feats[(size_t)n * 256 + t]);
    }
    out[g * 256 + t] = acc;
}

// ---------- launch ----------
extern "C" void kernel_launch(void* const* d_in, const int* in_sizes, int n_in,
                              void* d_out, int out_size, void* d_ws, size_t ws_size,
                              hipStream_t stream) {
    const float* x     = (const float*)d_in[0];
    const int*   batch = (const int*)d_in[1];
    const float* Wg2   = (const float*)d_in[3];
    const float* bn2   = (const float*)d_in[7];
    float* out = (float*)d_out;

    unsigned short* xb    = (unsigned short*)d_ws;            // MPAD*256
    unsigned short* h     = xb + (size_t)MPAD * 256;          // MPAD*512
    unsigned short* feats = h + (size_t)MPAD * 512;           // MPAD*256
    unsigned short* wcatT = feats + (size_t)MPAD * 256;       // 512*256
    unsigned short* wn2T  = wcatT + 512 * 256;                // 256*256
    float* biascat = (float*)(wn2T + 256 * 256);              // 512
    float* alpha   = biascat + 512;                           // NN*8

    convert_x<<<50016, 256, 0, stream>>>(x, xb);
    convert_w<<<770, 256, 0, stream>>>((const float*)d_in[2], (const float*)d_in[4],
                                       (const float*)d_in[6], (const float*)d_in[5],
                                       wcatT, wn2T, biascat);
    // h = relu(x @ [Wg1 | Wn1] + [0 | bn1])   -> [MPAD, 512] bf16
    // grid: x = column-block (fast) so panel re-reads stay L2-hot
    gemm_bt<<<dim3(4, 1563), 256, 0, stream>>>(xb, 256, wcatT, biascat, h, 512, 1);
    // alpha = h_g @ Wg2
    alpha_kernel<<<3125, 256, 0, stream>>>(h, Wg2, alpha);
    // feats = h_n @ Wn2 + bn2                 -> [MPAD, 256] bf16
    gemm_bt<<<dim3(2, 1563), 256, 0, stream>>>(h + 256, 512, wn2T, bn2, feats, 256, 0);
    // segment softmax + gated pooling
    pool_kernel<<<NGRAPH, 256, 0, stream>>>(alpha, feats, batch, out);
}

// Round 3
// 506.779 us; speedup vs baseline: 1.1982x; 1.1982x over previous
//
#include <hip/hip_runtime.h>

#define NN     200000
#define MPAD   200064   // 1563 * 128
#define KDIM   256
#define NHEAD  8
#define NGRAPH 1024
#define APAD   264      // padded LDS row for alpha kernel

typedef __bf16 bf16x8 __attribute__((ext_vector_type(8)));
typedef float  f32x4  __attribute__((ext_vector_type(4)));

// ---------- helpers ----------
__device__ __forceinline__ unsigned short f2bu(float f) {
    unsigned u = __float_as_uint(f);
    unsigned r = (u + 0x7FFFu + ((u >> 16) & 1u)) >> 16;
    return (unsigned short)r;
}
__device__ __forceinline__ float b2f(unsigned short u) {
    return __uint_as_float(((unsigned)u) << 16);
}
__device__ __forceinline__ void async16(const void* g, void* l) {
    __builtin_amdgcn_global_load_lds(
        (const __attribute__((address_space(1))) void*)g,
        (__attribute__((address_space(3))) void*)l, 16, 0, 0);
}

// ---------- kernel 1: cast x -> bf16, zero the 64 pad rows ----------
__global__ __launch_bounds__(256) void convert_x(const float* __restrict__ x,
                                                 unsigned short* __restrict__ xb) {
    size_t e = ((size_t)blockIdx.x * 256 + threadIdx.x) * 4;
    ushort4 o;
    if (e < (size_t)NN * 256) {
        float4 v = *(const float4*)(x + e);
        o.x = f2bu(v.x); o.y = f2bu(v.y); o.z = f2bu(v.z); o.w = f2bu(v.w);
    } else {
        o.x = o.y = o.z = o.w = 0;
    }
    *(ushort4*)(xb + e) = o;
}

// ---------- kernel 2: transpose-convert gate/node W1, build concat bias ----
__global__ __launch_bounds__(256) void convert_w(
    const float* __restrict__ Wg1, const float* __restrict__ Wn1,
    const float* __restrict__ bn1,
    unsigned short* __restrict__ wcatT, float* __restrict__ biascat) {
    int i = blockIdx.x * 256 + threadIdx.x;
    if (i < 512 * 256) {                       // wcatT[n][k] = Wcat[k][n]
        int n = i >> 8, k = i & 255;
        float v = (n < 256) ? Wg1[k * 256 + n] : Wn1[k * 256 + (n - 256)];
        wcatT[i] = f2bu(v);
    } else if (i < 512 * 256 + 512) {
        int b = i - 512 * 256;
        biascat[b] = (b < 256) ? 0.0f : bn1[b - 256];
    }
}

// ---------- kernel 3: bf16 MFMA GEMM, C = relu(A @ Bt^T + bias) ----------
// (unchanged from R2: 128x128 tile, BK=64, XOR-swizzled LDS, conflict-free)
__global__ __launch_bounds__(256) void gemm_bt(
    const unsigned short* __restrict__ A, int lda,
    const unsigned short* __restrict__ Bt,
    const float* __restrict__ bias,
    unsigned short* __restrict__ C, int ldc, int do_relu) {
    __shared__ unsigned short As[128 * 64];
    __shared__ unsigned short Bs[128 * 64];
    const int tid  = threadIdx.x;
    const int lane = tid & 63;
    const int wave = tid >> 6;
    const int wm = wave >> 1, wn = wave & 1;
    const size_t m0 = (size_t)blockIdx.y * 128;
    const int    n0 = blockIdx.x * 128;

    const int schunk = lane & 7;
    const int srow0  = wave * 32 + (lane >> 3);
    const int sw = ((schunk ^ (srow0 & 7)) * 8);
    const unsigned short* gA = A + (m0 + srow0) * (size_t)lda + sw;
    const unsigned short* gB = Bt + (size_t)(n0 + srow0) * KDIM + sw;
    unsigned short* lA = As + wave * 2048;
    unsigned short* lB = Bs + wave * 2048;

    f32x4 acc[4][4] = {};
    const int frow = lane & 15;
    const int quad = lane >> 4;
    const int arow = wm * 64 + frow;
    const int brow = wn * 64 + frow;

    for (int k0 = 0; k0 < KDIM; k0 += 64) {
        #pragma unroll
        for (int is = 0; is < 4; ++is) {
            async16(gA + (size_t)(is * 8) * lda + k0, lA + is * 512);
            async16(gB + (is * 8) * KDIM + k0, lB + is * 512);
        }
        __syncthreads();
        #pragma unroll
        for (int kk = 0; kk < 2; ++kk) {
            const int s = (quad + kk * 4) ^ (frow & 7);
            bf16x8 af[4], bf[4];
            #pragma unroll
            for (int i = 0; i < 4; ++i)
                af[i] = *(const bf16x8*)(As + (arow + i * 16) * 64 + s * 8);
            #pragma unroll
            for (int j = 0; j < 4; ++j)
                bf[j] = *(const bf16x8*)(Bs + (brow + j * 16) * 64 + s * 8);
            #pragma unroll
            for (int i = 0; i < 4; ++i)
                #pragma unroll
                for (int j = 0; j < 4; ++j)
                    acc[i][j] = __builtin_amdgcn_mfma_f32_16x16x32_bf16(
                        af[i], bf[j], acc[i][j], 0, 0, 0);
        }
        __syncthreads();
    }

    float bv[4];
    #pragma unroll
    for (int j = 0; j < 4; ++j) bv[j] = bias[n0 + wn * 64 + j * 16 + frow];
    const int rbase = wm * 64 + (quad << 2);
    #pragma unroll
    for (int i = 0; i < 4; ++i) {
        #pragma unroll
        for (int r = 0; r < 4; ++r) {
            size_t row = m0 + rbase + i * 16 + r;
            #pragma unroll
            for (int j = 0; j < 4; ++j) {
                float v = acc[i][j][r] + bv[j];
                if (do_relu) v = fmaxf(v, 0.0f);
                C[row * ldc + (n0 + wn * 64 + j * 16 + frow)] = f2bu(v);
            }
        }
    }
}

// ---------- kernel 4: alpha = h_g @ Wg2  (fp32 accum, LDS-staged) ----------
__global__ __launch_bounds__(256) void alpha_kernel(
    const unsigned short* __restrict__ h,   // [MPAD,512], cols 0..255 = h_g
    const float* __restrict__ Wg2,          // [256,8] fp32
    float* __restrict__ alpha) {            // [NN,8]
    __shared__ unsigned short hs[64 * APAD];
    __shared__ float wg[256 * 8];
    const int t = threadIdx.x;
    const size_t n0 = (size_t)blockIdx.x * 64;
    for (int i = t; i < 2048; i += 256) wg[i] = Wg2[i];
    #pragma unroll
    for (int it = 0; it < 16; ++it) {
        int e = (t + it * 256) * 4;
        int r = e >> 8, c = e & 255;
        *(ushort4*)&hs[r * APAD + c] = *(const ushort4*)(h + (n0 + r) * 512 + c);
    }
    __syncthreads();
    const int nl = t >> 2;
    const int hp = t & 3;
    float a0 = 0.f, a1 = 0.f;
    #pragma unroll 8
    for (int k = 0; k < 256; ++k) {
        float xv = b2f(hs[nl * APAD + k]);
        a0 += xv * wg[k * 8 + hp];
        a1 += xv * wg[k * 8 + hp + 4];
    }
    alpha[(n0 + nl) * 8 + hp]     = a0;
    alpha[(n0 + nl) * 8 + hp + 4] = a1;
}

// ---------- kernel 5: softmax + gated segment-sum of h_n + tiny GEMV ------
// out[g, c] = sum_k ( sum_{n in g} gate[n, c&7] * h_n[n,k] ) * Wn2[k,c]
//           + bn2[c] * (sum gate == 1 if graph nonempty)
__device__ __forceinline__ int lower_bound(const int* __restrict__ b, int key) {
    int lo = 0, hi = NN;
    while (lo < hi) { int mid = (lo + hi) >> 1; if (b[mid] < key) lo = mid + 1; else hi = mid; }
    return lo;
}

__global__ __launch_bounds__(256) void pool2(
    const float* __restrict__ alpha, const unsigned short* __restrict__ h,
    const float* __restrict__ Wn2, const float* __restrict__ bn2,
    const int* __restrict__ batch, float* __restrict__ out) {
    __shared__ float red[256];
    __shared__ float mh[8], ih[8];
    __shared__ float gate_s[32][8];
    __shared__ float Gs[256 * 8];
    const int g = blockIdx.x, t = threadIdx.x;
    const int start = lower_bound(batch, g);
    const int end   = lower_bound(batch, g + 1);
    const int hd = t & 7;

    // pass 1: per-head max over segment (coalesced: addr = start*8 + t)
    float mloc = -INFINITY;
    for (int n = start + (t >> 3); n < end; n += 32)
        mloc = fmaxf(mloc, alpha[n * 8 + hd]);
    red[t] = mloc; __syncthreads();
    for (int off = 128; off >= 8; off >>= 1) {
        if (t < off) red[t] = fmaxf(red[t], red[t + off]);
        __syncthreads();
    }
    if (t < 8) mh[t] = red[t];
    __syncthreads();
    const float mm = mh[hd];

    // pass 2: sum of exp
    float sloc = 0.f;
    for (int n = start + (t >> 3); n < end; n += 32)
        sloc += __expf(alpha[n * 8 + hd] - mm);
    red[t] = sloc; __syncthreads();
    for (int off = 128; off >= 8; off >>= 1) {
        if (t < off) red[t] += red[t + off];
        __syncthreads();
    }
    if (t < 8) ih[t] = 1.0f / (red[t] + 1e-16f);
    __syncthreads();

    // pass 3: G[k=t, hd=0..7] = sum_n gate[n,hd] * h_n[n, t]   (fp32 regs)
    float G[8] = {0.f, 0.f, 0.f, 0.f, 0.f, 0.f, 0.f, 0.f};
    for (int c0 = start; c0 < end; c0 += 32) {
        const int cn = min(32, end - c0);
        __syncthreads();
        if (t < cn * 8)
            gate_s[t >> 3][t & 7] =
                __expf(alpha[(c0 + (t >> 3)) * 8 + (t & 7)] - mh[t & 7]) * ih[t & 7];
        __syncthreads();
        for (int j = 0; j < cn; ++j) {
            float hv = b2f(h[(size_t)(c0 + j) * 512 + 256 + t]);
            float4 g0 = *(const float4*)&gate_s[j][0];   // LDS broadcast
            float4 g1 = *(const float4*)&gate_s[j][4];
            G[0] += g0.x * hv; G[1] += g0.y * hv; G[2] += g0.z * hv; G[3] += g0.w * hv;
            G[4] += g1.x * hv; G[5] += g1.y * hv; G[6] += g1.z * hv; G[7] += g1.w * hv;
        }
    }
    __syncthreads();
    *(float4*)&Gs[t * 8]     = *(const float4*)&G[0];
    *(float4*)&Gs[t * 8 + 4] = *(const float4*)&G[4];
    __syncthreads();

    // GEMV: out[g, t] = sum_k Gs[k, t&7] * Wn2[k, t] (+ bn2 if nonempty)
    float acc = 0.f;
    #pragma unroll 4
    for (int k = 0; k < 256; ++k)
        acc += Gs[k * 8 + hd] * Wn2[k * 256 + t];
    const float sg = (end > start) ? 1.0f : 0.0f;
    out[g * 256 + t] = acc + sg * bn2[t];
}

// ---------- launch ----------
extern "C" void kernel_launch(void* const* d_in, const int* in_sizes, int n_in,
                              void* d_out, int out_size, void* d_ws, size_t ws_size,
                              hipStream_t stream) {
    const float* x     = (const float*)d_in[0];
    const int*   batch = (const int*)d_in[1];
    const float* Wg2   = (const float*)d_in[3];
    const float* Wn2   = (const float*)d_in[6];
    const float* bn2   = (const float*)d_in[7];
    float* out = (float*)d_out;

    unsigned short* xb    = (unsigned short*)d_ws;            // MPAD*256
    unsigned short* h     = xb + (size_t)MPAD * 256;          // MPAD*512
    unsigned short* wcatT = h + (size_t)MPAD * 512;           // 512*256
    float* biascat = (float*)(wcatT + 512 * 256);             // 512
    float* alpha   = biascat + 512;                           // NN*8

    convert_x<<<50016, 256, 0, stream>>>(x, xb);
    convert_w<<<514, 256, 0, stream>>>((const float*)d_in[2], (const float*)d_in[4],
                                       (const float*)d_in[5], wcatT, biascat);
    // h = relu(x @ [Wg1 | Wn1] + [0 | bn1])   -> [MPAD, 512] bf16
    gemm_bt<<<dim3(4, 1563), 256, 0, stream>>>(xb, 256, wcatT, biascat, h, 512, 1);
    // alpha = h_g @ Wg2
    alpha_kernel<<<3125, 256, 0, stream>>>(h, Wg2, alpha);
    // softmax + gated segment-sum + final GEMV (replaces GEMM2 + pool)
    pool2<<<NGRAPH, 256, 0, stream>>>(alpha, h, Wn2, bn2, batch, out);
}

// Round 4
// 487.189 us; speedup vs baseline: 1.2464x; 1.0402x over previous
//
#include <hip/hip_runtime.h>

#define NN     200000
#define MPAD   200064   // 1563 * 128
#define KDIM   256
#define NGRAPH 1024

typedef __bf16 bf16x8 __attribute__((ext_vector_type(8)));
typedef float  f32x4  __attribute__((ext_vector_type(4)));
typedef float  f32x2  __attribute__((ext_vector_type(2)));

// ---------- helpers ----------
__device__ __forceinline__ unsigned short f2bu(float f) {
    unsigned u = __float_as_uint(f);
    unsigned r = (u + 0x7FFFu + ((u >> 16) & 1u)) >> 16;
    return (unsigned short)r;
}
__device__ __forceinline__ float b2f(unsigned short u) {
    return __uint_as_float(((unsigned)u) << 16);
}
__device__ __forceinline__ void async16(const void* g, void* l) {
    __builtin_amdgcn_global_load_lds(
        (const __attribute__((address_space(1))) void*)g,
        (__attribute__((address_space(3))) void*)l, 16, 0, 0);
}

// ---------- kernel 1: cast x -> bf16, zero the 64 pad rows ----------
__global__ __launch_bounds__(256) void convert_x(const float* __restrict__ x,
                                                 unsigned short* __restrict__ xb) {
    size_t e = ((size_t)blockIdx.x * 256 + threadIdx.x) * 4;
    ushort4 o;
    if (e < (size_t)NN * 256) {
        float4 v = *(const float4*)(x + e);
        o.x = f2bu(v.x); o.y = f2bu(v.y); o.z = f2bu(v.z); o.w = f2bu(v.w);
    } else {
        o.x = o.y = o.z = o.w = 0;
    }
    *(ushort4*)(xb + e) = o;
}

// ---------- kernel 2: weight prep ----------
// wcatT[n][k] = [Wg1|Wn1][k][n] bf16;  wg2T[16][256]: rows 0-7 = bf16 hi of
// Wg2 col h, rows 8-15 = bf16 residual (hi+lo MFMA = fp32-accurate Wg2).
__global__ __launch_bounds__(256) void convert_w(
    const float* __restrict__ Wg1, const float* __restrict__ Wn1,
    const float* __restrict__ bn1, const float* __restrict__ Wg2,
    unsigned short* __restrict__ wcatT, unsigned short* __restrict__ wg2T,
    float* __restrict__ biascat) {
    int i = blockIdx.x * 256 + threadIdx.x;
    if (i < 512 * 256) {
        int n = i >> 8, k = i & 255;
        float v = (n < 256) ? Wg1[k * 256 + n] : Wn1[k * 256 + (n - 256)];
        wcatT[i] = f2bu(v);
    } else if (i < 512 * 256 + 4096) {
        int j = i - 512 * 256;
        int hh = j >> 8, k = j & 255;            // hh 0..15
        float w = Wg2[k * 8 + (hh & 7)];
        unsigned short hi = f2bu(w);
        wg2T[j] = (hh < 8) ? hi : f2bu(w - b2f(hi));
    } else if (i < 512 * 256 + 4096 + 512) {
        int b = i - (512 * 256 + 4096);
        biascat[b] = (b < 256) ? 0.0f : bn1[b - 256];
    }
}

// ---------- kernel 3: h = relu(xb @ wcatT^T + bias), all 512 cols/block ----
// A panel (128x256, 64 KB) staged ONCE; B tiles (16 KB) staged per
// (col-tile, k-chunk) — B total 256 KB, L2-resident. XOR-swizzled LDS.
__global__ __launch_bounds__(256) void gemm_full(
    const unsigned short* __restrict__ A,     // [MPAD,256] bf16
    const unsigned short* __restrict__ Bt,    // [512,256]  bf16
    const float* __restrict__ bias,           // [512]
    unsigned short* __restrict__ C) {         // [MPAD,512] bf16
    __shared__ unsigned short As[128 * 256];  // 64 KB
    __shared__ unsigned short Bs[128 * 64];   // 16 KB
    const int tid  = threadIdx.x;
    const int lane = tid & 63;
    const int wave = tid >> 6;
    const int wm = wave >> 1, wn = wave & 1;
    const size_t m0 = (size_t)blockIdx.x * 128;
    const int frow = lane & 15;
    const int quad = lane >> 4;

    // ---- stage full A panel, swizzled: chunk c of row r -> slot c^(r&7)
    {
        const int roff = lane >> 5;           // 0/1
        const int s    = lane & 31;           // LDS chunk slot
        #pragma unroll
        for (int it = 0; it < 16; ++it) {
            int r = wave * 32 + it * 2 + roff;
            async16(A + (m0 + r) * 256 + ((s ^ (r & 7)) * 8),
                    As + (wave * 32 + it * 2) * 256);
        }
    }

    // B staging pattern (per col-tile ct, k-chunk kc)
    const int schunk = lane & 7;
    const int srow0  = wave * 32 + (lane >> 3);
    const int swb    = (schunk ^ (srow0 & 7)) * 8;
    unsigned short* lB = Bs + wave * 2048;

    #pragma unroll 1
    for (int ct = 0; ct < 4; ++ct) {
        const int n0 = ct * 128;
        f32x4 acc[4][4] = {};
        #pragma unroll 1
        for (int kc = 0; kc < 4; ++kc) {
            #pragma unroll
            for (int is = 0; is < 4; ++is)
                async16(Bt + (size_t)(n0 + srow0 + is * 8) * 256 + kc * 64 + swb,
                        lB + is * 512);
            __syncthreads();
            #pragma unroll
            for (int kk = 0; kk < 2; ++kk) {
                const int sa = (kc * 8 + kk * 4 + quad) ^ (frow & 7);
                const int sb = (kk * 4 + quad) ^ (frow & 7);
                bf16x8 af[4], bf[4];
                #pragma unroll
                for (int i = 0; i < 4; ++i)
                    af[i] = *(const bf16x8*)(As + (wm * 64 + i * 16 + frow) * 256 + sa * 8);
                #pragma unroll
                for (int j = 0; j < 4; ++j)
                    bf[j] = *(const bf16x8*)(Bs + (wn * 64 + j * 16 + frow) * 64 + sb * 8);
                #pragma unroll
                for (int i = 0; i < 4; ++i)
                    #pragma unroll
                    for (int j = 0; j < 4; ++j)
                        acc[i][j] = __builtin_amdgcn_mfma_f32_16x16x32_bf16(
                            af[i], bf[j], acc[i][j], 0, 0, 0);
            }
            __syncthreads();
        }
        // epilogue for this col-tile
        float bv[4];
        #pragma unroll
        for (int j = 0; j < 4; ++j) bv[j] = bias[n0 + wn * 64 + j * 16 + frow];
        const int rbase = wm * 64 + (quad << 2);
        #pragma unroll
        for (int i = 0; i < 4; ++i)
            #pragma unroll
            for (int r = 0; r < 4; ++r) {
                size_t row = m0 + rbase + i * 16 + r;
                #pragma unroll
                for (int j = 0; j < 4; ++j) {
                    float v = fmaxf(acc[i][j][r] + bv[j], 0.0f);
                    C[row * 512 + (n0 + wn * 64 + j * 16 + frow)] = f2bu(v);
                }
            }
    }
}

// ---------- kernel 4: alpha = h_g @ Wg2 via MFMA (hi+lo split) ----------
__global__ __launch_bounds__(256) void alpha_mfma(
    const unsigned short* __restrict__ h,     // [MPAD,512]; cols 0..255 = h_g
    const unsigned short* __restrict__ wg2T,  // [16,256] bf16
    float* __restrict__ alpha) {              // [NN,8]
    __shared__ unsigned short As[128 * 256];  // 64 KB
    const int tid  = threadIdx.x;
    const int lane = tid & 63;
    const int wave = tid >> 6;
    const int frow = lane & 15;
    const int quad = lane >> 4;
    const size_t m0 = (size_t)blockIdx.x * 128;

    {
        const int roff = lane >> 5;
        const int s    = lane & 31;
        #pragma unroll
        for (int it = 0; it < 16; ++it) {
            int r = wave * 32 + it * 2 + roff;
            async16(h + (m0 + r) * 512 + ((s ^ (r & 7)) * 8),
                    As + (wave * 32 + it * 2) * 256);
        }
    }
    bf16x8 bw[8];
    #pragma unroll
    for (int kk = 0; kk < 8; ++kk)
        bw[kk] = *(const bf16x8*)(wg2T + frow * 256 + kk * 32 + quad * 8);
    __syncthreads();

    f32x4 acc[2] = {};
    #pragma unroll
    for (int kk = 0; kk < 8; ++kk) {
        const int sa = (kk * 4 + quad) ^ (frow & 7);
        #pragma unroll
        for (int mt = 0; mt < 2; ++mt) {
            bf16x8 af = *(const bf16x8*)(As + (wave * 32 + mt * 16 + frow) * 256 + sa * 8);
            acc[mt] = __builtin_amdgcn_mfma_f32_16x16x32_bf16(af, bw[kk], acc[mt], 0, 0, 0);
        }
    }
    #pragma unroll
    for (int mt = 0; mt < 2; ++mt)
        #pragma unroll
        for (int r = 0; r < 4; ++r) {
            float v = acc[mt][r];
            v += __shfl_xor(v, 8);            // hi (col h) + lo (col h+8)
            size_t row = m0 + wave * 32 + mt * 16 + quad * 4 + r;
            if (frow < 8 && row < NN) alpha[row * 8 + frow] = v;
        }
}

// ---------- kernel 5: softmax + gated segment-sum + tiny GEMV ----------
__device__ __forceinline__ int lower_bound(const int* __restrict__ b, int key) {
    int lo = 0, hi = NN;
    while (lo < hi) { int mid = (lo + hi) >> 1; if (b[mid] < key) lo = mid + 1; else hi = mid; }
    return lo;
}

__global__ __launch_bounds__(256) void pool2(
    const float* __restrict__ alpha, const unsigned short* __restrict__ h,
    const float* __restrict__ Wn2, const float* __restrict__ bn2,
    const int* __restrict__ batch, float* __restrict__ out) {
    __shared__ float red[256];
    __shared__ float mh[8], ih[8];
    __shared__ float gate_s[32][8];
    __shared__ float Gs[256 * 8];
    const int g = blockIdx.x, t = threadIdx.x;
    const int start = lower_bound(batch, g);
    const int end   = lower_bound(batch, g + 1);
    const int hd = t & 7;

    float mloc = -INFINITY;
    for (int n = start + (t >> 3); n < end; n += 32)
        mloc = fmaxf(mloc, alpha[n * 8 + hd]);
    red[t] = mloc; __syncthreads();
    for (int off = 128; off >= 8; off >>= 1) {
        if (t < off) red[t] = fmaxf(red[t], red[t + off]);
        __syncthreads();
    }
    if (t < 8) mh[t] = red[t];
    __syncthreads();
    const float mm = mh[hd];

    float sloc = 0.f;
    for (int n = start + (t >> 3); n < end; n += 32)
        sloc += __expf(alpha[n * 8 + hd] - mm);
    red[t] = sloc; __syncthreads();
    for (int off = 128; off >= 8; off >>= 1) {
        if (t < off) red[t] += red[t + off];
        __syncthreads();
    }
    if (t < 8) ih[t] = 1.0f / (red[t] + 1e-16f);
    __syncthreads();

    // pass 3: G[k=t, 0..7] += gate[n,:] * h_n[n, t]  (f32x2 -> v_pk_fma_f32)
    f32x2 G2[4] = {};
    for (int c0 = start; c0 < end; c0 += 32) {
        const int cn = min(32, end - c0);
        __syncthreads();
        if (t < cn * 8)
            gate_s[t >> 3][t & 7] =
                __expf(alpha[(c0 + (t >> 3)) * 8 + (t & 7)] - mh[t & 7]) * ih[t & 7];
        __syncthreads();
        for (int j = 0; j < cn; ++j) {
            float hv = b2f(h[(size_t)(c0 + j) * 512 + 256 + t]);
            f32x2 h2 = {hv, hv};
            const f32x2* gp = (const f32x2*)&gate_s[j][0];   // LDS broadcast
            G2[0] += gp[0] * h2; G2[1] += gp[1] * h2;
            G2[2] += gp[2] * h2; G2[3] += gp[3] * h2;
        }
    }
    __syncthreads();
    #pragma unroll
    for (int i = 0; i < 4; ++i) *(f32x2*)&Gs[t * 8 + i * 2] = G2[i];
    __syncthreads();

    float acc = 0.f;
    #pragma unroll 4
    for (int k = 0; k < 256; ++k)
        acc += Gs[k * 8 + hd] * Wn2[k * 256 + t];
    const float sg = (end > start) ? 1.0f : 0.0f;
    out[g * 256 + t] = acc + sg * bn2[t];
}

// ---------- launch ----------
extern "C" void kernel_launch(void* const* d_in, const int* in_sizes, int n_in,
                              void* d_out, int out_size, void* d_ws, size_t ws_size,
                              hipStream_t stream) {
    const float* x     = (const float*)d_in[0];
    const int*   batch = (const int*)d_in[1];
    const float* Wg2   = (const float*)d_in[3];
    const float* Wn2   = (const float*)d_in[6];
    const float* bn2   = (const float*)d_in[7];
    float* out = (float*)d_out;

    unsigned short* xb    = (unsigned short*)d_ws;            // MPAD*256
    unsigned short* h     = xb + (size_t)MPAD * 256;          // MPAD*512
    unsigned short* wcatT = h + (size_t)MPAD * 512;           // 512*256
    unsigned short* wg2T  = wcatT + 512 * 256;                // 16*256
    float* biascat = (float*)(wg2T + 16 * 256);               // 512
    float* alpha   = biascat + 512;                           // NN*8

    convert_x<<<50016, 256, 0, stream>>>(x, xb);
    convert_w<<<531, 256, 0, stream>>>((const float*)d_in[2], (const float*)d_in[4],
                                       (const float*)d_in[5], Wg2,
                                       wcatT, wg2T, biascat);
    gemm_full<<<1563, 256, 0, stream>>>(xb, wcatT, biascat, h);
    alpha_mfma<<<1563, 256, 0, stream>>>(h, wg2T, alpha);
    pool2<<<NGRAPH, 256, 0, stream>>>(alpha, h, Wn2, bn2, batch, out);
}